// Round 1
// baseline (62.973 us; speedup 1.0000x reference)
//
#include <hip/hip_runtime.h>
#include <math.h>

// ProbAttention at B=1, L=S=128, H=8, D=1, u=25.
// Key simplifications (verified against the reference semantics):
//  * reshape(B,H,L,-1) on a (B,L,H,D) array with B=1,D=1 is a flat
//    reinterpretation -> q_flat[h*L + l].
//  * masked scores are where(mask, -inf, ZEROS) -> softmax is uniform over
//    the causal prefix l <= idx; upd = prefix-mean of v.
//  * cumsum over the size-1 D axis is identity -> ctx = v.
//  * scatter order of idx is irrelevant; only the top-k SET matters.
//    jax.lax.top_k tie-break = lowest index first -> rank with (>, or == && s<l).

#define LSEQ 128
#define NHEAD 8

__global__ __launch_bounds__(LSEQ) void probattn_kernel(
    const float* __restrict__ q, const float* __restrict__ k,
    const float* __restrict__ v, const int* __restrict__ kseq,
    float* __restrict__ out, int U) {
  const int h = blockIdx.x;
  const int l = threadIdx.x;  // 0..127

  __shared__ float Ks[64];     // gathered keys (U <= 64)
  __shared__ float M[LSEQ];    // sparsity measure per query position
  __shared__ float cums[LSEQ]; // inclusive prefix sum of v

  if (l < U) Ks[l] = k[h * LSEQ + kseq[l]];
  const float ql = q[h * LSEQ + l];
  const float vl = v[h * LSEQ + l];
  cums[l] = vl;
  __syncthreads();

  // M[l] = max_j(q*Ks_j) - sum_j(q*Ks_j)/S   (S = 128, /128 is exact)
  float mx = -INFINITY, sm = 0.0f;
  for (int j = 0; j < U; ++j) {
    const float p = ql * Ks[j];
    mx = fmaxf(mx, p);
    sm += p;
  }
  const float Ml = mx - sm * (1.0f / (float)LSEQ);
  M[l] = Ml;

  // Hillis-Steele inclusive scan of v over the 128 positions.
  for (int off = 1; off < LSEQ; off <<= 1) {
    __syncthreads();
    const float add = (l >= off) ? cums[l - off] : 0.0f;
    __syncthreads();
    cums[l] += add;
  }
  __syncthreads();  // M[] fully visible; cums[l] is self-written/self-read

  // rank of M[l] with top_k's lowest-index tie-break
  int rank = 0;
  for (int s = 0; s < LSEQ; ++s) {
    const float Ms = M[s];
    rank += (Ms > Ml) || (Ms == Ml && s < l);
  }

  out[h * LSEQ + l] = (rank < U) ? (cums[l] / (float)(l + 1)) : vl;
}

extern "C" void kernel_launch(void* const* d_in, const int* in_sizes, int n_in,
                              void* d_out, int out_size, void* d_ws, size_t ws_size,
                              hipStream_t stream) {
  const float* q = (const float*)d_in[0];
  const float* k = (const float*)d_in[1];
  const float* v = (const float*)d_in[2];
  const int* kseq = (const int*)d_in[3];
  float* out = (float*)d_out;
  const int U = in_sizes[3];  // 25

  probattn_kernel<<<NHEAD, LSEQ, 0, stream>>>(q, k, v, kseq, out, U);
}